// Round 5
// baseline (406.539 us; speedup 1.0000x reference)
//
#include <hip/hip_runtime.h>
#include <hip/hip_cooperative_groups.h>
#include <math.h>

namespace cg = cooperative_groups;

// Problem constants (fixed by the reference setup_inputs): B=2, P=8192, K=16
#define PP    8192
#define NPTS  16384
#define KNN   16
#define EPSV  1e-17f
#define NCELL 4096           // 16^3 Morton cells per batch
#define NTILE 128            // tiles of 64 sorted points per batch
#define KEY_BIG 3.0e38f      // > any real key, finite

__device__ __forceinline__ int cell_of(float x, float y, float z) {
    int cx = (int)floorf((x + 4.0f) * 2.0f); cx = min(15, max(0, cx));
    int cy = (int)floorf((y + 4.0f) * 2.0f); cy = min(15, max(0, cy));
    int cz = (int)floorf((z + 4.0f) * 2.0f); cz = min(15, max(0, cz));
#define MORT4(v) (((v)&1) | (((v)&2)<<2) | (((v)&4)<<4) | (((v)&8)<<6))
    return MORT4(cx) | (MORT4(cy) << 1) | (MORT4(cz) << 2);
#undef MORT4
}

// sorted-insertion via med3 identity (keys sorted ascending, all >= 0, finite)
__device__ __forceinline__ void insert16(float* keys, float key) {
#pragma unroll
    for (int s = KNN - 1; s >= 1; --s)
        keys[s] = __builtin_amdgcn_fmed3f(keys[s - 1], key, keys[s]);
    keys[0] = fminf(keys[0], key);
}

// ---- one cooperative kernel: sort -> aabb -> knn+phi+n1 -> denoise2 -> loss --
__global__ __launch_bounds__(512) void mega_kernel(
    const float* __restrict__ pts, const float* __restrict__ normals,
    float4* __restrict__ spts4, int* __restrict__ sid, float4* __restrict__ aabb,
    int* __restrict__ hist,
    int* __restrict__ out_idx, float* __restrict__ out_dist,
    float* __restrict__ phi_out, float* __restrict__ n1_out,
    float* __restrict__ nw_out, float* __restrict__ n2_out,
    float* __restrict__ out)
{
    __shared__ float4 lds_aabb[2 * NTILE];   // 4 KB
    __shared__ float4 batF[512];             // 8 KB  (seed + staged batches)
    __shared__ int    batI[512];             // 2 KB
    __shared__ float  smerge[8 * KNN * 64];  // 32 KB
    __shared__ int    sbuf[512];             // 2 KB  (scan)
    __shared__ unsigned int tau_u[64];
    __shared__ int    hitflag[120];
    __shared__ int    list_sh[124];
    __shared__ int    nlist_sh;

    const int tid  = threadIdx.x;
    const int bid  = blockIdx.x;
    const int lane = tid & 63;
    const int wave = tid >> 6;
    cg::grid_group grid = cg::this_grid();

    // ---- S0: zero histogram + output accumulator ----
    { const int g = bid * 512 + tid;
      if (g < 2 * NCELL) hist[g] = 0;
      if (g == 0) out[0] = 0.0f; }
    grid.sync();

    // ---- S1: cell histogram (blocks 0..31 active) ----
    { const int g = bid * 512 + tid;
      if (g < NPTS) {
          const int b = g >> 13;
          atomicAdd(&hist[b * NCELL + cell_of(pts[g*3], pts[g*3+1], pts[g*3+2])], 1);
      } }
    grid.sync();

    // ---- S2: exclusive scan -> cursors in place (blocks 0,1) ----
    if (bid < 2) {
        int* hh = hist + bid * NCELL;
        int loc[8]; int s = 0;
#pragma unroll
        for (int k = 0; k < 8; ++k) { loc[k] = s; s += hh[tid * 8 + k]; }
        sbuf[tid] = s; __syncthreads();
        for (int off = 1; off < 512; off <<= 1) {
            int v = (tid >= off) ? sbuf[tid - off] : 0;
            __syncthreads(); sbuf[tid] += v; __syncthreads();
        }
        const int excl = sbuf[tid] - s;
#pragma unroll
        for (int k = 0; k < 8; ++k) hh[tid * 8 + k] = excl + loc[k];
    }
    grid.sync();

    // ---- S3: scatter into Morton order ----
    { const int g = bid * 512 + tid;
      if (g < NPTS) {
          const int b = g >> 13, lp = g & (PP - 1);
          const float x = pts[g*3], y = pts[g*3+1], z = pts[g*3+2];
          const int pos = atomicAdd(&hist[b * NCELL + cell_of(x, y, z)], 1);
          spts4[b * PP + pos] = make_float4(x, y, z, x*x + y*y + z*z);
          sid[b * PP + pos] = lp;
      } }
    grid.sync();

    // ---- S4: per-tile AABB (block bid -> global tile bid), wave 0 ----
    if (wave == 0) {
        const float4 c = spts4[bid * 64 + lane];
        float lx = c.x, ly = c.y, lz = c.z, hx = c.x, hy = c.y, hz = c.z;
#pragma unroll
        for (int m = 1; m < 64; m <<= 1) {
            lx = fminf(lx, __shfl_xor(lx, m, 64));
            ly = fminf(ly, __shfl_xor(ly, m, 64));
            lz = fminf(lz, __shfl_xor(lz, m, 64));
            hx = fmaxf(hx, __shfl_xor(hx, m, 64));
            hy = fmaxf(hy, __shfl_xor(hy, m, 64));
            hz = fmaxf(hz, __shfl_xor(hz, m, 64));
        }
        if (lane == 0) {
            aabb[2 * bid + 0] = make_float4(lx, ly, lz, 0.f);
            aabb[2 * bid + 1] = make_float4(hx, hy, hz, 0.f);
        }
    }
    grid.sync();

    // ---- S5: grid-pruned exact 16-NN + fused phi/denoise1 ----
    const int batch = bid >> 7;
    const int t_q   = bid & (NTILE - 1);
    const int sbase = batch * PP;

    if (tid < 2 * NTILE) lds_aabb[tid] = aabb[batch * 2 * NTILE + tid];
    if (tid < 64) tau_u[tid] = 0xFFFFFFFFu;
    {   // stage seed tiles t_q..t_q+7 (coalesced, 512 threads)
        const int tt = (t_q + (tid >> 6)) & (NTILE - 1);
        batF[tid] = spts4[sbase + tt * 64 + (tid & 63)];
        batI[tid] = sid  [sbase + tt * 64 + (tid & 63)];
    }
    __syncthreads();

    const float4 q4  = batF[lane];                   // query = own tile, slot lane
    const int    qid = batI[lane];                   // original id 0..8191
    const float qx = q4.x, qy = q4.y, qz = q4.z, d2q = q4.w;

    float keys[KNN];
#pragma unroll
    for (int s = 0; s < KNN; ++s) keys[s] = KEY_BIG;

    // seed scan: stride-8 over 512 staged candidates, software-pipelined
    {
        float4 c4 = batF[wave]; int sj = batI[wave];
#pragma unroll 4
        for (int s8 = wave; s8 < 512; s8 += 8) {
            float4 c4n = c4; int sjn = sj;
            if (s8 + 8 < 512) { c4n = batF[s8 + 8]; sjn = batI[s8 + 8]; }
            const float dot = __builtin_fmaf(qz, c4.z,
                              __builtin_fmaf(qy, c4.y, qx * c4.x));
            const float d = __builtin_fmaf(-2.0f, dot, d2q + c4.w);
            const float dc = fmaxf(d, 0.0f);
            unsigned int kb = (__float_as_uint(dc) & 0xFFFFE000u) | (unsigned int)sj;
            float key = __uint_as_float(kb);
            if (sj == qid) key = KEY_BIG;            // exclude self
            insert16(keys, key);
            c4 = c4n; sj = sjn;
        }
    }
    // per-query tau: min over waves of partial 16th key (valid upper bound)
    atomicMin(&tau_u[lane], __float_as_uint(keys[KNN - 1]));
    __syncthreads();
    const float tauf = __uint_as_float(tau_u[lane]);

    // hit flags: wave w checks tiles t = w, w+8, ... (point-to-box vs per-q tau)
    for (int t = wave; t < 120; t += 8) {
        const int tt = (t_q + 8 + t) & (NTILE - 1);
        const float4 lo = lds_aabb[2 * tt + 0];
        const float4 hi = lds_aabb[2 * tt + 1];
        const float ax = fmaxf(fmaxf(lo.x - qx, qx - hi.x), 0.0f);
        const float ay = fmaxf(fmaxf(lo.y - qy, qy - hi.y), 0.0f);
        const float az = fmaxf(fmaxf(lo.z - qz, qz - hi.z), 0.0f);
        const float bd = ax * ax + ay * ay + az * az;
        const float bdk = __uint_as_float(__float_as_uint(bd) & 0xFFFFE000u);
        const unsigned long long bal = __ballot(bdk < tauf);
        if (lane == 0) hitflag[t] = (bal != 0ull) ? 1 : 0;
    }
    __syncthreads();
    if (wave == 0) {                                 // order-preserving compaction
        const bool pA = hitflag[lane] != 0;
        const unsigned long long balA = __ballot(pA);
        const int rankA = __popcll(balA & ((1ull << lane) - 1ull));
        if (pA) list_sh[rankA] = (t_q + 8 + lane) & (NTILE - 1);
        const int cA = __popcll(balA);
        const bool pB = (lane < 56) && (hitflag[64 + lane] != 0);
        const unsigned long long balB = __ballot(pB);
        const int rankB = __popcll(balB & ((1ull << lane) - 1ull));
        if (pB) list_sh[cA + rankB] = (t_q + 72 + lane) & (NTILE - 1);
        if (lane == 0) nlist_sh = cA + __popcll(balB);
    }
    __syncthreads();
    const int nlist = nlist_sh;

    // batched dense scan of listed tiles (8 tiles = 512 candidates per batch)
    for (int base = 0; base < nlist; base += 8) {
        const int rem = min(8, nlist - base);
        __syncthreads();                             // previous batch consumed
        if ((tid >> 6) < rem) {
            const int tt = list_sh[base + (tid >> 6)];
            batF[tid] = spts4[sbase + tt * 64 + (tid & 63)];
            batI[tid] = sid  [sbase + tt * 64 + (tid & 63)];
        }
        __syncthreads();
        bool need = false;                           // per-wave adaptive skip
        for (int r = 0; r < rem; ++r) {
            const int tt = list_sh[base + r];
            const float4 lo = lds_aabb[2 * tt + 0];
            const float4 hi = lds_aabb[2 * tt + 1];
            const float ax = fmaxf(fmaxf(lo.x - qx, qx - hi.x), 0.0f);
            const float ay = fmaxf(fmaxf(lo.y - qy, qy - hi.y), 0.0f);
            const float az = fmaxf(fmaxf(lo.z - qz, qz - hi.z), 0.0f);
            const float bd = ax * ax + ay * ay + az * az;
            const float bdk = __uint_as_float(__float_as_uint(bd) & 0xFFFFE000u);
            need = need || (bdk < keys[KNN - 1]);
        }
        if (__ballot(need) != 0ull) {
            const int lim = rem * 64;
            float4 c4 = batF[wave]; int sj = batI[wave];
            for (int s8 = wave; s8 < lim; s8 += 8) {
                float4 c4n = c4; int sjn = sj;
                if (s8 + 8 < lim) { c4n = batF[s8 + 8]; sjn = batI[s8 + 8]; }
                const float dot = __builtin_fmaf(qz, c4.z,
                                  __builtin_fmaf(qy, c4.y, qx * c4.x));
                const float d = __builtin_fmaf(-2.0f, dot, d2q + c4.w);
                const float dc = fmaxf(d, 0.0f);
                unsigned int kb = (__float_as_uint(dc) & 0xFFFFE000u) | (unsigned int)sj;
                float key = __uint_as_float(kb);
                if (sj == qid) key = KEY_BIG;
                insert16(keys, key);
                c4 = c4n; sj = sjn;
            }
        }
    }

    // tree merge of 8 per-wave top-16s (3 rounds, parallel)
    __syncthreads();
#pragma unroll
    for (int s = 0; s < KNN; ++s) smerge[(wave * KNN + s) * 64 + lane] = keys[s];
    for (int step = 1; step < 8; step <<= 1) {
        __syncthreads();
        if ((wave & (2 * step - 1)) == 0) {
            const int partner = wave + step;
#pragma unroll
            for (int s2 = 0; s2 < KNN; ++s2)
                insert16(keys, smerge[(partner * KNN + s2) * 64 + lane]);
            if (wave != 0) {
#pragma unroll
                for (int s = 0; s < KNN; ++s) smerge[(wave * KNN + s) * 64 + lane] = keys[s];
            }
        }
    }

    if (wave == 0) {   // epilogue: exact dists, idx, phi, n1 (verbatim semantics)
        const float* bp = pts + (size_t)batch * PP * 3;
        const float* bn = normals + (size_t)batch * PP * 3;
        const int qrow = batch * PP + qid;
        float d[KNN]; int jidx[KNN];
#pragma unroll
        for (int s = 0; s < KNN; ++s) {
            const int j = (int)(__float_as_uint(keys[s]) & 0x1FFFu);
            jidx[s] = j;
            out_idx[qrow * KNN + s] = j;
            const float x = bp[j * 3 + 0];
            const float y = bp[j * 3 + 1];
            const float z = bp[j * 3 + 2];
            const float dot = qx * x + qy * y + qz * z;
            const float dd = (d2q + (x * x + y * y + z * z)) - (dot + dot);
            const float dcl = fmaxf(dd, 0.0f);
            out_dist[qrow * KNN + s] = dcl;
            d[s] = dcl;
        }
        float d1 = d[0];
#pragma unroll
        for (int s = 1; s < KNN; ++s) d1 = fminf(d1, d[s]);
        const float s0 = d1 * 8.0f;                  // 2 * FILTER_SCALE^2
        const float sden = (s0 < EPSV) ? EPSV : s0;
        float sphi = 0.f, nx = 0.f, ny = 0.f, nz = 0.f;
#pragma unroll
        for (int s = 0; s < KNN; ++s) {
            const float w = fmaxf(1.0f - d[s] / sden, 0.0f);
            const float w2 = w * w;
            const float ph = w2 * w2;
            phi_out[qrow * KNN + s] = ph;
            const int j = jidx[s];
            nx += ph * bn[j * 3 + 0];
            ny += ph * bn[j * 3 + 1];
            nz += ph * bn[j * 3 + 2];
            sphi += ph;
        }
        const float den = (sphi < EPSV) ? EPSV : sphi;
        n1_out[qrow * 3 + 0] = nx / den;
        n1_out[qrow * 3 + 1] = ny / den;
        n1_out[qrow * 3 + 2] = nz / den;
    }
    grid.sync();

    // ---- S6: normal_w + second denoise (one query per lane of wave 0) ----
    if (tid < 64) {
        const int q = bid * 64 + tid;
        const int b = q >> 13;
        const int gbase = b * PP;
        const float INV_SIG = 1.0f / (0.75f * 0.75f);
        const float ax = n1_out[q * 3 + 0];
        const float ay = n1_out[q * 3 + 1];
        const float az = n1_out[q * 3 + 2];
        const float an = fmaxf(sqrtf(ax * ax + ay * ay + az * az), 1e-12f);
        const float rx = ax / an, ry = ay / an, rz = az / an;
        float swn = 0.f, ox = 0.f, oy = 0.f, oz = 0.f;
#pragma unroll
        for (int s = 0; s < KNN; ++s) {
            const int j = out_idx[q * KNN + s];
            const float bx = n1_out[(gbase + j) * 3 + 0];
            const float by = n1_out[(gbase + j) * 3 + 1];
            const float bz = n1_out[(gbase + j) * 3 + 2];
            const float bnn = fmaxf(sqrtf(bx * bx + by * by + bz * bz), 1e-12f);
            const float ux = bx / bnn - rx;
            const float uy = by / bnn - ry;
            const float uz = bz / bnn - rz;
            const float dd = ux * ux + uy * uy + uz * uz;
            const float nw = expf(-dd * INV_SIG);
            nw_out[q * KNN + s] = nw;
            const float wk = phi_out[q * KNN + s] * nw;
            ox += wk * bx;
            oy += wk * by;
            oz += wk * bz;
            swn += wk;
        }
        const float den2 = (swn < EPSV) ? EPSV : swn;
        n2_out[q * 3 + 0] = ox / den2;
        n2_out[q * 3 + 1] = oy / den2;
        n2_out[q * 3 + 2] = oz / den2;
    }
    grid.sync();

    // ---- S7: weights_proj + point-to-plane loss + atomic mean ----
    if (tid < 64) {
        const int q = bid * 64 + tid;
        const int b = q >> 13;
        const int il = q & (PP - 1);
        const float* bp = pts + (size_t)b * PP * 3;
        const int gbase = b * PP;
        const float px = bp[il * 3 + 0];
        const float py = bp[il * 3 + 1];
        const float pz = bp[il * 3 + 2];
        float d[KNN];
#pragma unroll
        for (int s = 0; s < KNN; ++s) d[s] = out_dist[q * KNN + s];
        float d1 = d[0];
#pragma unroll
        for (int s = 1; s < KNN; ++s) d1 = fminf(d1, d[s]);
        const float thresh = 4.0f * d1;              // FILTER_SCALE * d1 * 2
        float num = 0.f, den = 0.f;
#pragma unroll
        for (int s = 0; s < KNN; ++s) {
            float w = phi_out[q * KNN + s] * nw_out[q * KNN + s];
            if (d[s] > thresh) w = 0.f;              // ball-query mask
            const int j = out_idx[q * KNN + s];
            const float nx = n2_out[(gbase + j) * 3 + 0];
            const float ny = n2_out[(gbase + j) * 3 + 1];
            const float nz = n2_out[(gbase + j) * 3 + 2];
            const float dts = (bp[j * 3 + 0] - px) * nx +
                              (bp[j * 3 + 1] - py) * ny +
                              (bp[j * 3 + 2] - pz) * nz;
            num += dts * dts * w;
            den += w;
        }
        const float dd2 = (den < EPSV) ? EPSV : den;
        float loss = num / dd2;
#pragma unroll
        for (int off = 32; off >= 1; off >>= 1) loss += __shfl_down(loss, off, 64);
        if (tid == 0) atomicAdd(out, loss * (1.0f / (float)NPTS));
    }
}

// ---- launch -----------------------------------------------------------------
extern "C" void kernel_launch(void* const* d_in, const int* in_sizes, int n_in,
                              void* d_out, int out_size, void* d_ws, size_t ws_size,
                              hipStream_t stream) {
    const float* points  = (const float*)d_in[0];   // (2, 8192, 3) f32
    const float* normals = (const float*)d_in[1];   // (2, 8192, 3) f32
    float* out = (float*)d_out;                     // scalar f32

    // workspace layout (floats):
    // idx @0 (262144) | dist @262144 | phi @524288 |
    // scratch @786432: spts4(65536) | sid @851968 (16384) | aabb @868352 (2048)
    //                  | hist @876544 (8192)  -- all dead before nw overwrites
    // nw @786432 (262144, written in S6) | n1 @1048576 | n2 @1097728
    float* wsf      = (float*)d_ws;
    int*    w_idx   = (int*)wsf;
    float*  w_dist  = wsf + 262144;
    float*  w_phi   = wsf + 524288;
    float*  w_nw    = wsf + 786432;
    float4* w_spts  = (float4*)(wsf + 786432);
    int*    w_sid   = (int*)(wsf + 851968);
    float4* w_aabb  = (float4*)(wsf + 868352);
    int*    w_hist  = (int*)(wsf + 876544);
    float*  w_n1    = wsf + 1048576;
    float*  w_n2    = wsf + 1097728;

    void* args[] = {
        (void*)&points, (void*)&normals,
        (void*)&w_spts, (void*)&w_sid, (void*)&w_aabb, (void*)&w_hist,
        (void*)&w_idx, (void*)&w_dist, (void*)&w_phi, (void*)&w_n1,
        (void*)&w_nw, (void*)&w_n2, (void*)&out
    };
    hipLaunchCooperativeKernel((const void*)mega_kernel, dim3(256), dim3(512),
                               args, 0, stream);
}

// Round 6
// 199.606 us; speedup vs baseline: 2.0367x; 2.0367x over previous
//
#include <hip/hip_runtime.h>
#include <math.h>

// Problem constants (fixed by the reference setup_inputs): B=2, P=8192, K=16
#define PP    8192
#define NPTS  16384
#define KNN   16
#define EPSV  1e-17f
#define NCELL 4096           // 16^3 Morton cells per batch
#define NTILE 128            // tiles of 64 sorted points per batch
#define KEY_BIG 3.0e38f      // > any real key, finite

__device__ __forceinline__ int cell_of(float x, float y, float z) {
    int cx = (int)floorf((x + 4.0f) * 2.0f); cx = min(15, max(0, cx));
    int cy = (int)floorf((y + 4.0f) * 2.0f); cy = min(15, max(0, cy));
    int cz = (int)floorf((z + 4.0f) * 2.0f); cz = min(15, max(0, cz));
#define MORT4(v) (((v)&1) | (((v)&2)<<2) | (((v)&4)<<4) | (((v)&8)<<6))
    return MORT4(cx) | (MORT4(cy) << 1) | (MORT4(cz) << 2);
#undef MORT4
}

// sorted-insertion via med3 identity (keys ascending, all >= 0, finite)
__device__ __forceinline__ void insert16(float* keys, float key) {
#pragma unroll
    for (int s = KNN - 1; s >= 1; --s)
        keys[s] = __builtin_amdgcn_fmed3f(keys[s - 1], key, keys[s]);
    keys[0] = fminf(keys[0], key);
}

// ---- K0: fused counting sort + tile AABBs, one block per batch --------------
__global__ __launch_bounds__(1024) void sort_kernel(const float* __restrict__ pts,
                                                    float4* __restrict__ spts4,
                                                    int* __restrict__ sid,
                                                    float4* __restrict__ aabb,
                                                    float* __restrict__ out) {
    __shared__ int h[NCELL];         // histogram, then cursors
    __shared__ int sbuf[1024];
    const int t = threadIdx.x;
    const int batch = blockIdx.x;
    const float* bp = pts + (size_t)batch * PP * 3;

    if (batch == 0 && t == 0) out[0] = 0.0f;        // accumulator for K2
    for (int k = t; k < NCELL; k += 1024) h[k] = 0;
    __syncthreads();

    float px[8], py[8], pz[8]; int pc[8];
#pragma unroll
    for (int k = 0; k < 8; ++k) {
        const int p = k * 1024 + t;                  // coalesced
        const float x = bp[p * 3 + 0];
        const float y = bp[p * 3 + 1];
        const float z = bp[p * 3 + 2];
        px[k] = x; py[k] = y; pz[k] = z;
        const int c = cell_of(x, y, z);
        pc[k] = c;
        atomicAdd(&h[c], 1);
    }
    __syncthreads();

    int loc[4]; int s = 0;
#pragma unroll
    for (int k = 0; k < 4; ++k) { loc[k] = s; s += h[t * 4 + k]; }
    sbuf[t] = s; __syncthreads();
    for (int off = 1; off < 1024; off <<= 1) {
        int v = (t >= off) ? sbuf[t - off] : 0;
        __syncthreads();
        sbuf[t] += v;
        __syncthreads();
    }
    const int excl = sbuf[t] - s;
#pragma unroll
    for (int k = 0; k < 4; ++k) h[t * 4 + k] = excl + loc[k];   // cursors
    __syncthreads();

    const int sbase = batch * PP;
#pragma unroll
    for (int k = 0; k < 8; ++k) {
        const int pos = atomicAdd(&h[pc[k]], 1);
        const int p = k * 1024 + t;
        spts4[sbase + pos] = make_float4(px[k], py[k], pz[k],
                                         px[k]*px[k] + py[k]*py[k] + pz[k]*pz[k]);
        sid[sbase + pos] = p;
    }
    __syncthreads();

    if (t < NTILE) {                                 // per-tile AABB
        float4 c0 = spts4[sbase + t * 64];
        float lx = c0.x, ly = c0.y, lz = c0.z, hx = c0.x, hy = c0.y, hz = c0.z;
        for (int e = 1; e < 64; ++e) {
            float4 c = spts4[sbase + t * 64 + e];
            lx = fminf(lx, c.x); ly = fminf(ly, c.y); lz = fminf(lz, c.z);
            hx = fmaxf(hx, c.x); hy = fmaxf(hy, c.y); hz = fmaxf(hz, c.z);
        }
        aabb[(batch * NTILE + t) * 2 + 0] = make_float4(lx, ly, lz, 0.f);
        aabb[(batch * NTILE + t) * 2 + 1] = make_float4(hx, hy, hz, 0.f);
    }
}

// ---- K1: grid-pruned exact 16-NN + fused phi/denoise1 -----------------------
// 256 blocks x 512. Block = 64 queries (sorted tile t_q), 8 waves.
// Seed: symmetric Morton window t_q-3..t_q+4 (512 cands, stride-8 per wave)
// -> per-query tau (min over waves, LDS atomicMin). Hit list over the other
// 120 tiles via point-to-box < tau (exact superset). Batched coalesced
// staging (8 tiles/batch, 2 barriers), per-tile ballot skip vs live keys[15].
__global__ __launch_bounds__(512) void knn_kernel(const float* __restrict__ pts,
                                                  const float* __restrict__ normals,
                                                  const float4* __restrict__ spts4,
                                                  const int* __restrict__ sid,
                                                  const float4* __restrict__ aabb,
                                                  int* __restrict__ out_idx,
                                                  float* __restrict__ out_dist,
                                                  float* __restrict__ phi_out,
                                                  float* __restrict__ n1_out) {
    __shared__ float4 lds_aabb[2 * NTILE];           // 4 KB
    __shared__ float4 batF[512];                     // 8 KB
    __shared__ int    batI[512];                     // 2 KB
    __shared__ float  smerge[8 * KNN * 64];          // 32 KB
    __shared__ unsigned int tau_u[64];
    __shared__ int    hitflag[120];
    __shared__ int    list_sh[124];
    __shared__ int    nlist_sh;

    const int tid   = threadIdx.x;
    const int lane  = tid & 63;
    const int wave  = tid >> 6;
    const int batch = blockIdx.x >> 7;
    const int t_q   = blockIdx.x & (NTILE - 1);
    const int sbase = batch * PP;

    if (tid < 2 * NTILE) lds_aabb[tid] = aabb[batch * 2 * NTILE + tid];
    if (tid < 64) tau_u[tid] = 0xFFFFFFFFu;
    {   // stage seed tiles t_q-3..t_q+4 (wave w -> tile t_q+w-3), coalesced
        const int tt = (t_q + wave + (NTILE - 3)) & (NTILE - 1);
        batF[tid] = spts4[sbase + tt * 64 + lane];
        batI[tid] = sid  [sbase + tt * 64 + lane];
    }
    __syncthreads();

    const float4 q4  = batF[192 + lane];             // own tile = seed slot 3
    const int    qid = batI[192 + lane];             // original id 0..8191
    const float qx = q4.x, qy = q4.y, qz = q4.z, d2q = q4.w;

    float keys[KNN];
#pragma unroll
    for (int s = 0; s < KNN; ++s) keys[s] = KEY_BIG;

    // seed scan: stride-8 over 512 staged candidates (LDS broadcast)
    for (int s8 = wave; s8 < 512; s8 += 8) {
        const float4 c4 = batF[s8];
        const int sj = batI[s8];
        const float dot = __builtin_fmaf(qz, c4.z,
                          __builtin_fmaf(qy, c4.y, qx * c4.x));
        const float d = __builtin_fmaf(-2.0f, dot, d2q + c4.w);
        const float dc = fmaxf(d, 0.0f);
        unsigned int kb = (__float_as_uint(dc) & 0xFFFFE000u) | (unsigned int)sj;
        float key = __uint_as_float(kb);
        if (sj == qid) key = KEY_BIG;                // exclude self
        insert16(keys, key);
    }
    atomicMin(&tau_u[lane], __float_as_uint(keys[KNN - 1]));
    __syncthreads();
    const float tauf = __uint_as_float(tau_u[lane]);

    // hit flags over the 120 non-seed tiles (offsets +5..+124 mod 128)
    for (int t = wave; t < 120; t += 8) {
        const int tt = (t_q + 5 + t) & (NTILE - 1);
        const float4 lo = lds_aabb[2 * tt + 0];
        const float4 hi = lds_aabb[2 * tt + 1];
        const float ax = fmaxf(fmaxf(lo.x - qx, qx - hi.x), 0.0f);
        const float ay = fmaxf(fmaxf(lo.y - qy, qy - hi.y), 0.0f);
        const float az = fmaxf(fmaxf(lo.z - qz, qz - hi.z), 0.0f);
        const float bd = ax * ax + ay * ay + az * az;
        const float bdk = __uint_as_float(__float_as_uint(bd) & 0xFFFFE000u);
        const unsigned long long bal = __ballot(bdk < tauf);
        if (lane == 0) hitflag[t] = (bal != 0ull) ? 1 : 0;
    }
    __syncthreads();
    if (wave == 0) {                                 // order-preserving compaction
        const bool pA = hitflag[lane] != 0;
        const unsigned long long balA = __ballot(pA);
        const int rankA = __popcll(balA & ((1ull << lane) - 1ull));
        if (pA) list_sh[rankA] = (t_q + 5 + lane) & (NTILE - 1);
        const int cA = __popcll(balA);
        const bool pB = (lane < 56) && (hitflag[64 + lane] != 0);
        const unsigned long long balB = __ballot(pB);
        const int rankB = __popcll(balB & ((1ull << lane) - 1ull));
        if (pB) list_sh[cA + rankB] = (t_q + 69 + lane) & (NTILE - 1);
        if (lane == 0) nlist_sh = cA + __popcll(balB);
    }
    __syncthreads();
    const int nlist = nlist_sh;

    // batched scan: 8 tiles (512 cands) per staging round, per-tile skip
    for (int base = 0; base < nlist; base += 8) {
        const int rem = min(8, nlist - base);
        __syncthreads();                             // previous batch consumed
        if (wave < rem) {
            const int tt = list_sh[base + wave];
            batF[tid] = spts4[sbase + tt * 64 + lane];
            batI[tid] = sid  [sbase + tt * 64 + lane];
        }
        __syncthreads();
        for (int r = 0; r < rem; ++r) {
            const int tt = list_sh[base + r];
            const float4 lo = lds_aabb[2 * tt + 0];
            const float4 hi = lds_aabb[2 * tt + 1];
            const float ax = fmaxf(fmaxf(lo.x - qx, qx - hi.x), 0.0f);
            const float ay = fmaxf(fmaxf(lo.y - qy, qy - hi.y), 0.0f);
            const float az = fmaxf(fmaxf(lo.z - qz, qz - hi.z), 0.0f);
            const float bd = ax * ax + ay * ay + az * az;
            const float bdk = __uint_as_float(__float_as_uint(bd) & 0xFFFFE000u);
            if (__ballot(bdk < keys[KNN - 1]) == 0ull) continue;
#pragma unroll
            for (int k = 0; k < 8; ++k) {
                const int jj = r * 64 + wave + 8 * k;
                const float4 c4 = batF[jj];
                const int sj = batI[jj];             // sj != qid (non-seed tile)
                const float dot = __builtin_fmaf(qz, c4.z,
                                  __builtin_fmaf(qy, c4.y, qx * c4.x));
                const float d = __builtin_fmaf(-2.0f, dot, d2q + c4.w);
                const float dc = fmaxf(d, 0.0f);
                unsigned int kb = (__float_as_uint(dc) & 0xFFFFE000u) | (unsigned int)sj;
                insert16(keys, __uint_as_float(kb));
            }
        }
    }

    // tree merge of 8 per-wave top-16s (3 rounds)
    __syncthreads();
#pragma unroll
    for (int s = 0; s < KNN; ++s) smerge[(wave * KNN + s) * 64 + lane] = keys[s];
    for (int step = 1; step < 8; step <<= 1) {
        __syncthreads();
        if ((wave & (2 * step - 1)) == 0) {
            const int partner = wave + step;
#pragma unroll
            for (int s2 = 0; s2 < KNN; ++s2)
                insert16(keys, smerge[(partner * KNN + s2) * 64 + lane]);
            if (wave != 0) {
#pragma unroll
                for (int s = 0; s < KNN; ++s) smerge[(wave * KNN + s) * 64 + lane] = keys[s];
            }
        }
    }

    if (wave == 0) {   // epilogue: exact dists, idx, phi, n1 (verbatim semantics)
        const float* bp = pts + (size_t)batch * PP * 3;
        const float* bn = normals + (size_t)batch * PP * 3;
        const int qrow = batch * PP + qid;
        float d[KNN]; int jidx[KNN];
#pragma unroll
        for (int s = 0; s < KNN; ++s) {
            const int j = (int)(__float_as_uint(keys[s]) & 0x1FFFu);
            jidx[s] = j;
            out_idx[qrow * KNN + s] = j;
            const float x = bp[j * 3 + 0];
            const float y = bp[j * 3 + 1];
            const float z = bp[j * 3 + 2];
            const float dot = qx * x + qy * y + qz * z;
            const float dd = (d2q + (x * x + y * y + z * z)) - (dot + dot);
            const float dcl = fmaxf(dd, 0.0f);
            out_dist[qrow * KNN + s] = dcl;
            d[s] = dcl;
        }
        float d1 = d[0];
#pragma unroll
        for (int s = 1; s < KNN; ++s) d1 = fminf(d1, d[s]);
        const float s0 = d1 * 8.0f;                  // 2 * FILTER_SCALE^2
        const float sden = (s0 < EPSV) ? EPSV : s0;
        float sphi = 0.f, nx = 0.f, ny = 0.f, nz = 0.f;
#pragma unroll
        for (int s = 0; s < KNN; ++s) {
            const float w = fmaxf(1.0f - d[s] / sden, 0.0f);
            const float w2 = w * w;
            const float ph = w2 * w2;
            phi_out[qrow * KNN + s] = ph;
            const int j = jidx[s];
            nx += ph * bn[j * 3 + 0];
            ny += ph * bn[j * 3 + 1];
            nz += ph * bn[j * 3 + 2];
            sphi += ph;
        }
        const float den = (sphi < EPSV) ? EPSV : sphi;
        n1_out[qrow * 3 + 0] = nx / den;
        n1_out[qrow * 3 + 1] = ny / den;
        n1_out[qrow * 3 + 2] = nz / den;
    }
}

// ---- K2: fused normal_w + denoise2-recompute + loss + atomic mean -----------
// One thread per (query q, neighbor slot j). n2[jj] and nw recomputed from
// idx/dist/phi/n1 with expressions bitwise-identical to the R2 kernels.
__global__ __launch_bounds__(256) void loss_kernel(const float* __restrict__ pts,
                                                   const int* __restrict__ idx,
                                                   const float* __restrict__ dist,
                                                   const float* __restrict__ phi,
                                                   const float* __restrict__ n1,
                                                   float* __restrict__ out) {
    __shared__ float red[4];
    const int g = blockIdx.x * 256 + threadIdx.x;    // 0 .. 262143
    const int q = g >> 4;
    const int j = g & 15;
    const int b = q >> 13;
    const int il = q & (PP - 1);
    const int gbase = b * PP;
    const float* bp = pts + (size_t)b * PP * 3;
    const float INV_SIG = 1.0f / (0.75f * 0.75f);

    // per-q threshold: group-min of dists over the 16 lanes of this q
    const float dj = dist[q * KNN + j];
    float d1 = dj;
#pragma unroll
    for (int m = 1; m < 16; m <<= 1) d1 = fminf(d1, __shfl_xor(d1, m, 16));
    const float thresh = 4.0f * d1;                  // FILTER_SCALE * d1 * 2

    const int jj = idx[q * KNN + j];                 // neighbor original id

    // normalize(n1[q]) and normalize(n1[jj])
    const float aqx = n1[q * 3 + 0], aqy = n1[q * 3 + 1], aqz = n1[q * 3 + 2];
    const float anq = fmaxf(sqrtf(aqx*aqx + aqy*aqy + aqz*aqz), 1e-12f);
    const float rqx = aqx / anq, rqy = aqy / anq, rqz = aqz / anq;

    const float ajx = n1[(gbase + jj) * 3 + 0];
    const float ajy = n1[(gbase + jj) * 3 + 1];
    const float ajz = n1[(gbase + jj) * 3 + 2];
    const float anj = fmaxf(sqrtf(ajx*ajx + ajy*ajy + ajz*ajz), 1e-12f);
    const float rjx = ajx / anj, rjy = ajy / anj, rjz = ajz / anj;

    // nw(q,j)
    const float ex = rjx - rqx, ey = rjy - rqy, ez = rjz - rqz;
    const float nwq = expf(-(ex*ex + ey*ey + ez*ez) * INV_SIG);
    float w = phi[q * KNN + j] * nwq;
    if (dj > thresh) w = 0.f;                        // ball-query mask

    // recompute n2[jj] = denoise(n1, idx[jj], phi[jj]*nw[jj])  (bitwise same)
    float swn = 0.f, ox = 0.f, oy = 0.f, oz = 0.f;
#pragma unroll
    for (int s = 0; s < KNN; ++s) {
        const int js = idx[(gbase + jj) * KNN + s];
        const float bx = n1[(gbase + js) * 3 + 0];
        const float by = n1[(gbase + js) * 3 + 1];
        const float bz = n1[(gbase + js) * 3 + 2];
        const float bnn = fmaxf(sqrtf(bx*bx + by*by + bz*bz), 1e-12f);
        const float ux = bx / bnn - rjx;
        const float uy = by / bnn - rjy;
        const float uz = bz / bnn - rjz;
        const float dd = ux*ux + uy*uy + uz*uz;
        const float nws = expf(-dd * INV_SIG);
        const float wk = phi[(gbase + jj) * KNN + s] * nws;
        ox += wk * bx;
        oy += wk * by;
        oz += wk * bz;
        swn += wk;
    }
    const float den2 = (swn < EPSV) ? EPSV : swn;
    const float n2x = ox / den2, n2y = oy / den2, n2z = oz / den2;

    // signed point-to-plane distance
    const float px = bp[il * 3 + 0];
    const float py = bp[il * 3 + 1];
    const float pz = bp[il * 3 + 2];
    const float dts = (bp[jj * 3 + 0] - px) * n2x +
                      (bp[jj * 3 + 1] - py) * n2y +
                      (bp[jj * 3 + 2] - pz) * n2z;
    float num = dts * dts * w;
    float den = w;

    // reduce over the 16 lanes of q, then sum the 4 q-groups of the wave
#pragma unroll
    for (int m = 1; m < 16; m <<= 1) {
        num += __shfl_xor(num, m, 16);
        den += __shfl_xor(den, m, 16);
    }
    const float ddv = (den < EPSV) ? EPSV : den;
    float v = num / ddv;                             // identical across 16 lanes
    v += __shfl_xor(v, 16, 64);
    v += __shfl_xor(v, 32, 64);                      // sum of 4 group losses
    if ((threadIdx.x & 63) == 0) red[threadIdx.x >> 6] = v;
    __syncthreads();
    if (threadIdx.x == 0)
        atomicAdd(out, (red[0] + red[1] + red[2] + red[3]) * (1.0f / (float)NPTS));
}

// ---- launch -----------------------------------------------------------------
extern "C" void kernel_launch(void* const* d_in, const int* in_sizes, int n_in,
                              void* d_out, int out_size, void* d_ws, size_t ws_size,
                              hipStream_t stream) {
    const float* points  = (const float*)d_in[0];   // (2, 8192, 3) f32
    const float* normals = (const float*)d_in[1];   // (2, 8192, 3) f32
    float* out = (float*)d_out;                     // scalar f32

    // workspace (floats): idx @0 | dist @262144 | phi @524288 | n1 @786432
    // | spts4 @835584 | sid @901120 | aabb @917504 (2048)
    float* wsf      = (float*)d_ws;
    int*    w_idx   = (int*)wsf;                     // 262144 ints
    float*  w_dist  = wsf + 262144;                  // 262144
    float*  w_phi   = wsf + 524288;                  // 262144
    float*  w_n1    = wsf + 786432;                  // 49152
    float4* w_spts  = (float4*)(wsf + 835584);       // 16384 float4
    int*    w_sid   = (int*)(wsf + 901120);          // 16384 ints
    float4* w_aabb  = (float4*)(wsf + 917504);       // 512 float4

    sort_kernel<<<2, 1024, 0, stream>>>(points, w_spts, w_sid, w_aabb, out);
    knn_kernel<<<256, 512, 0, stream>>>(points, normals, w_spts, w_sid, w_aabb,
                                        w_idx, w_dist, w_phi, w_n1);
    loss_kernel<<<1024, 256, 0, stream>>>(points, w_idx, w_dist, w_phi, w_n1, out);
}